// Round 3
// baseline (1035.431 us; speedup 1.0000x reference)
//
#include <hip/hip_runtime.h>
#include <hip/hip_bf16.h>
#include <stdint.h>
#include <stddef.h>

typedef __hip_bfloat16 bf16_t;
typedef _Float16 f16_t;
typedef f16_t h8 __attribute__((ext_vector_type(8)));
typedef f16_t h4 __attribute__((ext_vector_type(4)));
typedef float f4 __attribute__((ext_vector_type(4)));
typedef float f16v __attribute__((ext_vector_type(16)));

#define L_TOK 32768
#define S_SEG 2048
#define D_ 256

__device__ __forceinline__ float fsigmoid(float x){ return __builtin_amdgcn_rcpf(1.0f + __builtin_amdgcn_exp2f(-1.44269504f*x)); }
__device__ __forceinline__ float ftanh(float x){ return 1.0f - 2.0f*__builtin_amdgcn_rcpf(1.0f + __builtin_amdgcn_exp2f(2.88539008f*x)); }

// ---------------- prep kernels ----------------

// concat [berthid | posl[lp] | posr[rp]] -> Acat f16 [32768][832]
__global__ void k_cat(const float* __restrict__ bh, const int* __restrict__ lp, const int* __restrict__ rp,
                      const float* __restrict__ posl, const float* __restrict__ posr, f16_t* __restrict__ out)
{
    int i = blockIdx.x; int t = threadIdx.x;
    const float* r = bh + (size_t)i*768;
    f16_t* o = out + (size_t)i*832;
    o[t]       = (f16_t)r[t];
    o[256 + t] = (f16_t)r[256 + t];
    o[512 + t] = (f16_t)r[512 + t];
    if (t < 32)        o[768 + t] = (f16_t)posl[(size_t)lp[i]*32 + t];
    else if (t < 64)   o[768 + t] = (f16_t)posr[(size_t)rp[i]*32 + (t - 32)];
}

// transpose+convert: src f32 [K][N] -> dst f16 [N][K]
__global__ void k_transcvt(const float* __restrict__ src, f16_t* __restrict__ dst, int K, int N)
{
    __shared__ float tl[32][33];
    int kb = blockIdx.x*32, nb = blockIdx.y*32;
    int tx = threadIdx.x & 31, ty = threadIdx.x >> 5;
    #pragma unroll
    for (int i = ty; i < 32; i += 8) tl[i][tx] = src[(size_t)(kb+i)*N + nb + tx];
    __syncthreads();
    #pragma unroll
    for (int i = ty; i < 32; i += 8) dst[(size_t)(nb+i)*K + kb + tx] = (f16_t)tl[tx][i];
}

// flat f32 -> f16
__global__ void k_cvt(const float* __restrict__ src, f16_t* __restrict__ dst, int n)
{
    int i = blockIdx.x*256 + threadIdx.x;
    if (i < n) dst[i] = (f16_t)src[i];
}

// conv weight reorder: src [co][ci][T] -> dst [co][t*256+ci]
__global__ void k_convw(const float* __restrict__ src, f16_t* __restrict__ dst, int T, int total)
{
    int i = blockIdx.x*256 + threadIdx.x;
    if (i >= total) return;
    int co = i / (256*T); int rem = i - co*256*T; int t = rem >> 8; int ci = rem & 255;
    dst[i] = (f16_t)src[(size_t)co*256*T + ci*T + t];
}

// ex = entemb[ent_type]
__global__ void k_ex(const float* __restrict__ emb, const int* __restrict__ et, f16_t* __restrict__ out)
{
    int i = blockIdx.x*256 + threadIdx.x;
    out[i] = (f16_t)emb[(size_t)et[i >> 8]*256 + (i & 255)];
}

// transpose v [2048][256] -> vt [256][2048]
__global__ void k_vt(const f16_t* __restrict__ vb, f16_t* __restrict__ vt)
{
    __shared__ f16_t tl[32][33];
    int tb = blockIdx.x*32, cb = blockIdx.y*32;
    int tx = threadIdx.x & 31, ty = threadIdx.x >> 5;
    #pragma unroll
    for (int i = ty; i < 32; i += 8) tl[i][tx] = vb[(size_t)(tb+i)*256 + cb + tx];
    __syncthreads();
    #pragma unroll
    for (int i = ty; i < 32; i += 8) vt[(size_t)(cb+i)*2048 + tb + tx] = tl[tx][i];
}

// ---------------- GEMM (f16 MFMA, fp32 accum) ----------------
// C[m][n] = act( sum_k A[aoff(m)+k] * Bt[n][k] + bias[n] )
// aoff(m) = (m>>4)*aG1 + (m&15)*aG2 ; C index = (m>>4)*cG1 + (m&15)*cG2 + cG3 + n
__launch_bounds__(256, 2)
__global__ void k_gemm(const f16_t* __restrict__ A, const f16_t* __restrict__ Bt,
                       const float* __restrict__ bias, f16_t* __restrict__ C,
                       int K, int aG1, int aG2, int cG1, int cG2, int cG3, int relu)
{
    __shared__ f16_t As[128*40];
    __shared__ f16_t Bs[128*40];
    const int tid = threadIdx.x;
    const int lane = tid & 63, wave = tid >> 6;
    const int wm = (wave >> 1) * 64, wn = (wave & 1) * 64;
    const int m0 = blockIdx.x * 128, n0 = blockIdx.y * 128;
    const int l31 = lane & 31, lh = lane >> 5;

    f16v acc[4] = {};

    const int sr = tid >> 2, ss = tid & 3;
    const int gr1 = m0 + sr, gr2 = gr1 + 64;
    const size_t aoff1 = (size_t)(gr1 >> 4)*aG1 + (size_t)(gr1 & 15)*aG2 + ss*8;
    const size_t aoff2 = (size_t)(gr2 >> 4)*aG1 + (size_t)(gr2 & 15)*aG2 + ss*8;
    const size_t boff1 = (size_t)(n0 + sr)*K + ss*8;
    const size_t boff2 = (size_t)(n0 + sr + 64)*K + ss*8;

    for (int ki = 0; ki < K; ki += 32) {
        h8 av1 = *(const h8*)(A + aoff1 + ki);
        h8 av2 = *(const h8*)(A + aoff2 + ki);
        h8 bv1 = *(const h8*)(Bt + boff1 + ki);
        h8 bv2 = *(const h8*)(Bt + boff2 + ki);
        __syncthreads();
        *(h8*)&As[sr*40 + ss*8]        = av1;
        *(h8*)&As[(sr+64)*40 + ss*8]   = av2;
        *(h8*)&Bs[sr*40 + ss*8]        = bv1;
        *(h8*)&Bs[(sr+64)*40 + ss*8]   = bv2;
        __syncthreads();
        #pragma unroll
        for (int kk = 0; kk < 2; ++kk) {
            h8 a0 = *(const h8*)&As[(wm + l31)*40      + kk*16 + lh*8];
            h8 a1 = *(const h8*)&As[(wm + 32 + l31)*40 + kk*16 + lh*8];
            h8 b0 = *(const h8*)&Bs[(wn + l31)*40      + kk*16 + lh*8];
            h8 b1 = *(const h8*)&Bs[(wn + 32 + l31)*40 + kk*16 + lh*8];
            acc[0] = __builtin_amdgcn_mfma_f32_32x32x16_f16(a0, b0, acc[0], 0, 0, 0);
            acc[1] = __builtin_amdgcn_mfma_f32_32x32x16_f16(a0, b1, acc[1], 0, 0, 0);
            acc[2] = __builtin_amdgcn_mfma_f32_32x32x16_f16(a1, b0, acc[2], 0, 0, 0);
            acc[3] = __builtin_amdgcn_mfma_f32_32x32x16_f16(a1, b1, acc[3], 0, 0, 0);
        }
    }

    #pragma unroll
    for (int mi = 0; mi < 2; ++mi)
    #pragma unroll
    for (int ni = 0; ni < 2; ++ni) {
        int coln = n0 + wn + ni*32 + l31;
        float bvv = bias[coln];
        #pragma unroll
        for (int reg = 0; reg < 16; ++reg) {
            int row = wm + mi*32 + (reg & 3) + 8*(reg >> 2) + 4*lh;
            int gr = m0 + row;
            float v = acc[mi*2+ni][reg] + bvv;
            if (relu) v = fmaxf(v, 0.0f);
            size_t off = (size_t)(gr >> 4)*cG1 + (size_t)(gr & 15)*cG2 + cG3 + coln;
            C[off] = (f16_t)v;
        }
    }
}

// ---------------- pool / elementwise ----------------

__global__ void k_pool(const f16_t* __restrict__ c2, f16_t* __restrict__ seg)
{
    int s = blockIdx.x, d = threadIdx.x;
    const f16_t* p = c2 + (size_t)s*16*256 + d;
    float m = (float)p[0];
    #pragma unroll
    for (int i = 1; i < 16; ++i) m = fmaxf(m, (float)p[(size_t)i*256]);
    seg[(size_t)s*256 + d] = (f16_t)m;
}

__global__ void k_copyseg(const f16_t* __restrict__ seg, f16_t* __restrict__ gcat)
{
    int i = blockIdx.x*256 + threadIdx.x;
    int s = i >> 8, d = i & 255;
    gcat[(size_t)s*512 + 256 + d] = seg[i];
}

__global__ void k_fuse(const f16_t* __restrict__ gp, const f16_t* __restrict__ gcat,
                       const f16_t* __restrict__ seg, f16_t* __restrict__ fused)
{
    int i = blockIdx.x*256 + threadIdx.x;
    int s = i >> 8, d = i & 255;
    float g = (float)gp[i], gin = (float)gcat[(size_t)s*512 + d], sv = (float)seg[i];
    fused[i] = (f16_t)(g*gin + (1.0f - g)*sv);
}

// ---------------- attention (two-stream flash, MFMA) ----------------
__launch_bounds__(256, 2)
__global__ void k_attn(const f16_t* __restrict__ qb, const f16_t* __restrict__ kb,
                       const f16_t* __restrict__ qeb, const f16_t* __restrict__ keb,
                       const f16_t* __restrict__ vt, f16_t* __restrict__ ctx)
{
    __shared__ f16_t pbuf[4][2][16][20];
    const int tid = threadIdx.x, lane = tid & 63, w = tid >> 6;
    const int hh = blockIdx.y;
    const int q0 = (blockIdx.x*4 + w) * 16;
    const int quad = lane >> 4, l16 = lane & 15;

    const size_t qoff = (size_t)(q0 + l16)*256 + hh*32 + quad*8;
    h8 aq  = *(const h8*)(qb + qoff);
    h8 aqe = *(const h8*)(qeb + qoff);

    f4 zero4 = {};
    f4 ox0 = {}, ox1 = {}, oe0 = {}, oe1 = {};
    float mx[4], lx[4], me[4], le[4];
    #pragma unroll
    for (int r = 0; r < 4; ++r) { mx[r] = -1e4f; me[r] = -1e4f; lx[r] = 0.f; le[r] = 0.f; }

    for (int t0 = 0; t0 < 2048; t0 += 16) {
        const size_t koff = (size_t)(t0 + l16)*256 + hh*32 + quad*8;
        h8 bk  = *(const h8*)(kb + koff);
        h8 bke = *(const h8*)(keb + koff);
        f4 sx = __builtin_amdgcn_mfma_f32_16x16x32_f16(aq,  bk,  zero4, 0, 0, 0);
        f4 se = __builtin_amdgcn_mfma_f32_16x16x32_f16(aqe, bke, zero4, 0, 0, 0);
        float ax[4], ae[4];
        #pragma unroll
        for (int r = 0; r < 4; ++r) {
            float cm = sx[r];
            cm = fmaxf(cm, __shfl_xor(cm, 1, 64)); cm = fmaxf(cm, __shfl_xor(cm, 2, 64));
            cm = fmaxf(cm, __shfl_xor(cm, 4, 64)); cm = fmaxf(cm, __shfl_xor(cm, 8, 64));
            float mn = fmaxf(mx[r], cm);
            float p  = __builtin_amdgcn_exp2f((sx[r] - mn)*1.44269504f);
            float al = __builtin_amdgcn_exp2f((mx[r] - mn)*1.44269504f);
            float rs = p;
            rs += __shfl_xor(rs, 1, 64); rs += __shfl_xor(rs, 2, 64);
            rs += __shfl_xor(rs, 4, 64); rs += __shfl_xor(rs, 8, 64);
            lx[r] = lx[r]*al + rs; mx[r] = mn; ax[r] = al;
            pbuf[w][0][quad*4 + r][l16] = (f16_t)p;

            float cm2 = se[r];
            cm2 = fmaxf(cm2, __shfl_xor(cm2, 1, 64)); cm2 = fmaxf(cm2, __shfl_xor(cm2, 2, 64));
            cm2 = fmaxf(cm2, __shfl_xor(cm2, 4, 64)); cm2 = fmaxf(cm2, __shfl_xor(cm2, 8, 64));
            float mn2 = fmaxf(me[r], cm2);
            float p2  = __builtin_amdgcn_exp2f((se[r] - mn2)*1.44269504f);
            float al2 = __builtin_amdgcn_exp2f((me[r] - mn2)*1.44269504f);
            float rs2 = p2;
            rs2 += __shfl_xor(rs2, 1, 64); rs2 += __shfl_xor(rs2, 2, 64);
            rs2 += __shfl_xor(rs2, 4, 64); rs2 += __shfl_xor(rs2, 8, 64);
            le[r] = le[r]*al2 + rs2; me[r] = mn2; ae[r] = al2;
            pbuf[w][1][quad*4 + r][l16] = (f16_t)p2;
        }
        asm volatile("s_waitcnt lgkmcnt(0)" ::: "memory");
        h4 px = *(const h4*)&pbuf[w][0][l16][quad*4];
        h4 pe = *(const h4*)&pbuf[w][1][l16][quad*4];
        #pragma unroll
        for (int r = 0; r < 4; ++r) { ox0[r]*=ax[r]; ox1[r]*=ax[r]; oe0[r]*=ae[r]; oe1[r]*=ae[r]; }
        const size_t vo = (size_t)(hh*32 + l16)*2048 + t0 + quad*4;
        h4 bv0 = *(const h4*)(vt + vo);
        h4 bv1 = *(const h4*)(vt + vo + (size_t)16*2048);
        ox0 = __builtin_amdgcn_mfma_f32_16x16x16f16(px, bv0, ox0, 0, 0, 0);
        ox1 = __builtin_amdgcn_mfma_f32_16x16x16f16(px, bv1, ox1, 0, 0, 0);
        oe0 = __builtin_amdgcn_mfma_f32_16x16x16f16(pe, bv0, oe0, 0, 0, 0);
        oe1 = __builtin_amdgcn_mfma_f32_16x16x16f16(pe, bv1, oe1, 0, 0, 0);
    }
    #pragma unroll
    for (int r = 0; r < 4; ++r) {
        float ix = __builtin_amdgcn_rcpf(lx[r]), ie = __builtin_amdgcn_rcpf(le[r]);
        size_t o = (size_t)(q0 + quad*4 + r)*256 + hh*32;
        ctx[o + l16]      = (f16_t)(0.8f*ox0[r]*ix + 0.2f*oe0[r]*ie);
        ctx[o + 16 + l16] = (f16_t)(0.8f*ox1[r]*ix + 0.2f*oe1[r]*ie);
    }
}

// ---------------- GRU recurrence (chunked scan, W_hh register-resident) ----------------
#define GRU_NBLK 8
#define GRU_CH 16
#define GRU_CLEN 16
#define GRU_WARM 48

__launch_bounds__(512, 2)
__global__ void k_gru(const f16_t* __restrict__ gi, const f16_t* __restrict__ whh,
                      const float* __restrict__ bhh, f16_t* __restrict__ out0,
                      f16_t* __restrict__ out1, int layer)
{
    __shared__ f16_t hbuf[2][16][264];
    const int tid = threadIdx.x;
    const int dir = blockIdx.x & 1;
    const int grp = blockIdx.x >> 1;
    const int lane = tid & 63, w = tid >> 6;
    const int quad = lane >> 4, l16 = lane & 15;

    const int jt0 = 2*w, jt1 = 2*w + 1;  // r tiles; +16 z; +32 n

    h8 bf[6][8];
    #pragma unroll
    for (int j = 0; j < 6; ++j) {
        int jj = (j & 1) ? jt1 : jt0;
        int jtile = jj + (j >> 1)*16;
        const f16_t* wrow = whh + ((size_t)(dir*768 + 16*jtile + l16))*256 + quad*8;
        #pragma unroll
        for (int kk = 0; kk < 8; ++kk) bf[j][kk] = *(const h8*)(wrow + kk*32);
    }
    // index map: bf[2*g + jj] , g=0(r),1(z),2(n), jj in {0,1}
    float bhv[6];
    #pragma unroll
    for (int j = 0; j < 6; ++j) {
        int jj = (j & 1) ? jt1 : jt0;
        int jtile = jj + (j >> 1)*16;
        bhv[j] = bhh[dir*768 + 16*jtile + l16];
    }

    for (int i = tid; i < 2*16*264; i += 512) ((f16_t*)hbuf)[i] = (f16_t)0.0f;
    __syncthreads();

    const int u0 = 32*w + l16;
    const f16_t* gbase = gi + dir*768;
    f16_t* op = (layer == 0) ? out0 : (dir ? out1 : out0);
    const int ostride = (layer == 0) ? 512 : 256;
    const int ocol = (layer == 0) ? dir*256 : 0;
    const int mstart = grp * GRU_CH;

    #pragma unroll 1
    for (int s = 0; s < GRU_CLEN + GRU_WARM; ++s) {
        const int cur = s & 1, nxt = cur ^ 1;
        int tR[4]; int tC[4];
        #pragma unroll
        for (int r = 0; r < 4; ++r) {
            int m = quad*4 + r;
            int st = (mstart + m) * GRU_CLEN;
            tR[r] = (dir == 0) ? (st + s - GRU_WARM) : (st + GRU_CLEN - 1 + GRU_WARM - s);
            tC[r] = tR[r] < 0 ? 0 : (tR[r] > 2047 ? 2047 : tR[r]);
        }
        float gr_[4][2], gz_[4][2], gn_[4][2];
        #pragma unroll
        for (int r = 0; r < 4; ++r) {
            const f16_t* g = gbase + (size_t)tC[r]*1536;
            #pragma unroll
            for (int jj = 0; jj < 2; ++jj) {
                gr_[r][jj] = (float)g[u0 + 16*jj];
                gz_[r][jj] = (float)g[u0 + 16*jj + 256];
                gn_[r][jj] = (float)g[u0 + 16*jj + 512];
            }
        }
        f4 acc[6];
        #pragma unroll
        for (int j = 0; j < 6; ++j) { f4 t = {bhv[j], bhv[j], bhv[j], bhv[j]}; acc[j] = t; }
        #pragma unroll
        for (int kk = 0; kk < 8; ++kk) {
            h8 af = *(const h8*)&hbuf[cur][l16][kk*32 + quad*8];
            #pragma unroll
            for (int j = 0; j < 6; ++j)
                acc[j] = __builtin_amdgcn_mfma_f32_16x16x32_f16(af, bf[j][kk], acc[j], 0, 0, 0);
        }
        #pragma unroll
        for (int jj = 0; jj < 2; ++jj) {
            #pragma unroll
            for (int r = 0; r < 4; ++r) {
                int m = quad*4 + r;
                float rg = fsigmoid(gr_[r][jj] + acc[0*2 + jj][r]);
                float zg = fsigmoid(gz_[r][jj] + acc[1*2 + jj][r]);
                float nn = ftanh(gn_[r][jj] + rg*acc[2*2 + jj][r]);
                float hold = (float)hbuf[cur][m][u0 + 16*jj];
                float hnew = nn + zg*(hold - nn);
                if (tR[r] < 0 || tR[r] > 2047) hnew = 0.0f;
                hbuf[nxt][m][u0 + 16*jj] = (f16_t)hnew;
                if (s >= GRU_WARM) op[(size_t)tR[r]*ostride + ocol + u0 + 16*jj] = (f16_t)hnew;
            }
        }
        __syncthreads();
    }
}

// ---------------- finals ----------------

__global__ void k_f0(const f16_t* __restrict__ a, const f16_t* __restrict__ b,
                     float* __restrict__ my, float* __restrict__ dout)
{
    int i = blockIdx.x*256 + threadIdx.x;
    float v = (float)a[i] + (float)b[i];
    my[i] = v;
    dout[i] = v;
}

__global__ void k_f1(const float* __restrict__ my, const int* __restrict__ symi,
                     const float* __restrict__ sw1, const float* __restrict__ sw2,
                     const float* __restrict__ sc, float* __restrict__ small)
{
    __shared__ float sym[256];
    __shared__ float red[256];
    int d = threadIdx.x;
    int si = symi[0];
    float sv = my[(size_t)si*256 + d];
    sym[d] = sv;
    __syncthreads();
    float acc = 0.f;
    for (int j = 0; j < 256; ++j) acc += sw1[(size_t)j*256 + d] * sym[j];
    small[d] = acc + sw2[d];           // wcomb
    red[d] = sv * sw2[256 + d];
    __syncthreads();
    for (int o = 128; o > 0; o >>= 1) { if (d < o) red[d] += red[d + o]; __syncthreads(); }
    if (d == 0) small[256] = red[0] + sc[0];
}

__global__ void k_f2(const float* __restrict__ my, const float* __restrict__ small,
                     float* __restrict__ outp)
{
    int s = blockIdx.x*4 + (threadIdx.x >> 6);
    int lane = threadIdx.x & 63;
    float a = 0.f;
    #pragma unroll
    for (int i = 0; i < 4; ++i) a += my[(size_t)s*256 + lane + i*64] * small[lane + i*64];
    a += __shfl_xor(a, 32, 64); a += __shfl_xor(a, 16, 64); a += __shfl_xor(a, 8, 64);
    a += __shfl_xor(a, 4, 64);  a += __shfl_xor(a, 2, 64);  a += __shfl_xor(a, 1, 64);
    if (lane == 0) outp[s] = fsigmoid(a + small[256]);
}

// ---------------- host ----------------

extern "C" void kernel_launch(void* const* d_in, const int* in_sizes, int n_in,
                              void* d_out, int out_size, void* d_ws, size_t ws_size,
                              hipStream_t stream)
{
    (void)in_sizes; (void)n_in; (void)out_size; (void)ws_size;
    const float* berthid = (const float*)d_in[0];
    const int* lp  = (const int*)d_in[1];
    const int* rp  = (const int*)d_in[2];
    const int* et  = (const int*)d_in[3];
    const int* symi= (const int*)d_in[4];
    const float* posl = (const float*)d_in[5];
    const float* posr = (const float*)d_in[6];
    const float* space_w = (const float*)d_in[7];
    const float* space_b = (const float*)d_in[8];
    const float* entemb  = (const float*)d_in[9];
    const float* conv1_w = (const float*)d_in[10];
    const float* conv1_b = (const float*)d_in[11];
    const float* conv2_w = (const float*)d_in[12];
    const float* conv2_b = (const float*)d_in[13];
    const float* wq  = (const float*)d_in[14];
    const float* wk  = (const float*)d_in[15];
    const float* wv  = (const float*)d_in[16];
    const float* ewq = (const float*)d_in[17];
    const float* ewk = (const float*)d_in[18];
    const float* out_w = (const float*)d_in[19];
    const float* sw1 = (const float*)d_in[20];
    const float* b_q = (const float*)d_in[21];
    const float* b_k = (const float*)d_in[22];
    const float* b_v = (const float*)d_in[23];
    const float* eb_q= (const float*)d_in[24];
    const float* eb_k= (const float*)d_in[25];
    const float* out_b = (const float*)d_in[26];
    const float* gate_w = (const float*)d_in[27];
    const float* gate_b = (const float*)d_in[28];
    const float* wih0 = (const float*)d_in[29];
    const float* whh0 = (const float*)d_in[30];
    const float* bih0 = (const float*)d_in[31];
    const float* bhh0 = (const float*)d_in[32];
    const float* wih1 = (const float*)d_in[33];
    const float* whh1 = (const float*)d_in[34];
    const float* bih1 = (const float*)d_in[35];
    const float* bhh1 = (const float*)d_in[36];
    const float* sw2  = (const float*)d_in[37];
    const float* scorec = (const float*)d_in[38];

    char* wsb = (char*)d_ws;
    size_t o = 0;
    auto take = [&](size_t n){ size_t r = o; o = (o + n + 255) & ~(size_t)255; return r; };
    const size_t acat_o  = take((size_t)L_TOK*832*2);           // 54.5 MB, reused after proj
    const size_t xpad1_o = take((size_t)S_SEG*18*256*2);
    const size_t xpad2_o = take((size_t)S_SEG*20*256*2);
    const size_t spaceT_o= take(256*832*2);
    const size_t c1T_o   = take(256*768*2);
    const size_t c2T_o   = take((size_t)256*1280*2);
    const size_t wqT_o   = take(256*256*2);
    const size_t wkT_o   = take(256*256*2);
    const size_t wvT_o   = take(256*256*2);
    const size_t ewqT_o  = take(256*256*2);
    const size_t ewkT_o  = take(256*256*2);
    const size_t outwT_o = take(256*256*2);
    const size_t gatewT_o= take(256*512*2);
    const size_t wih0_o  = take((size_t)2*768*256*2);
    const size_t whh0_o  = take((size_t)2*768*256*2);
    const size_t wih1_o  = take((size_t)2*768*512*2);
    const size_t whh1_o  = take((size_t)2*768*256*2);
    const size_t ex_o    = take((size_t)S_SEG*256*2);   // written pre-proj: must NOT overlay Acat

    // overlay region inside Acat (Acat dead after proj GEMM; c2out = first 16.8 MB)
    size_t so = acat_o + 17825792;
    auto sub = [&](size_t n){ size_t r = so; so = (so + n + 255) & ~(size_t)255; return r; };
    const size_t c2out_o = acat_o;
    const size_t seg_o  = sub((size_t)S_SEG*256*2);
    const size_t q_o    = sub((size_t)S_SEG*256*2);
    const size_t k_o    = sub((size_t)S_SEG*256*2);
    const size_t v_o    = sub((size_t)S_SEG*256*2);
    const size_t qe_o   = sub((size_t)S_SEG*256*2);
    const size_t ke_o   = sub((size_t)S_SEG*256*2);
    const size_t vt_o   = sub((size_t)S_SEG*256*2);
    const size_t ctx_o  = sub((size_t)S_SEG*256*2);
    const size_t gcat_o = sub((size_t)S_SEG*512*2);
    const size_t gp_o   = sub((size_t)S_SEG*256*2);
    const size_t fus_o  = sub((size_t)S_SEG*256*2);
    const size_t gi0_o  = sub((size_t)S_SEG*1536*2);
    const size_t l0_o   = sub((size_t)S_SEG*512*2);
    const size_t gi1_o  = sub((size_t)S_SEG*1536*2);
    const size_t md0_o  = sub((size_t)S_SEG*256*2);
    const size_t md1_o  = sub((size_t)S_SEG*256*2);
    const size_t my_o   = sub((size_t)S_SEG*256*4);
    const size_t sm_o   = sub(4096);

    f16_t* Acat  = (f16_t*)(wsb + acat_o);
    f16_t* xpad1 = (f16_t*)(wsb + xpad1_o);
    f16_t* xpad2 = (f16_t*)(wsb + xpad2_o);
    f16_t* spaceT= (f16_t*)(wsb + spaceT_o);
    f16_t* c1T   = (f16_t*)(wsb + c1T_o);
    f16_t* c2T   = (f16_t*)(wsb + c2T_o);
    f16_t* wqT   = (f16_t*)(wsb + wqT_o);
    f16_t* wkT   = (f16_t*)(wsb + wkT_o);
    f16_t* wvT   = (f16_t*)(wsb + wvT_o);
    f16_t* ewqT  = (f16_t*)(wsb + ewqT_o);
    f16_t* ewkT  = (f16_t*)(wsb + ewkT_o);
    f16_t* outwT = (f16_t*)(wsb + outwT_o);
    f16_t* gatewT= (f16_t*)(wsb + gatewT_o);
    f16_t* wih0c = (f16_t*)(wsb + wih0_o);
    f16_t* whh0c = (f16_t*)(wsb + whh0_o);
    f16_t* wih1c = (f16_t*)(wsb + wih1_o);
    f16_t* whh1c = (f16_t*)(wsb + whh1_o);
    f16_t* c2out = (f16_t*)(wsb + c2out_o);
    f16_t* exb   = (f16_t*)(wsb + ex_o);
    f16_t* segb  = (f16_t*)(wsb + seg_o);
    f16_t* qbuf  = (f16_t*)(wsb + q_o);
    f16_t* kbuf  = (f16_t*)(wsb + k_o);
    f16_t* vbuf  = (f16_t*)(wsb + v_o);
    f16_t* qebuf = (f16_t*)(wsb + qe_o);
    f16_t* kebuf = (f16_t*)(wsb + ke_o);
    f16_t* vtb   = (f16_t*)(wsb + vt_o);
    f16_t* ctxb  = (f16_t*)(wsb + ctx_o);
    f16_t* gcat  = (f16_t*)(wsb + gcat_o);
    f16_t* gpb   = (f16_t*)(wsb + gp_o);
    f16_t* fusb  = (f16_t*)(wsb + fus_o);
    f16_t* gi0b  = (f16_t*)(wsb + gi0_o);
    f16_t* l0b   = (f16_t*)(wsb + l0_o);
    f16_t* gi1b  = (f16_t*)(wsb + gi1_o);
    f16_t* md0   = (f16_t*)(wsb + md0_o);
    f16_t* md1   = (f16_t*)(wsb + md1_o);
    float* myf   = (float*)(wsb + my_o);
    float* smallf= (float*)(wsb + sm_o);
    float* doutp = (float*)d_out;

    (void)hipMemsetAsync(wsb + xpad1_o, 0, (size_t)S_SEG*18*256*2, stream);
    (void)hipMemsetAsync(wsb + xpad2_o, 0, (size_t)S_SEG*20*256*2, stream);

    // prep
    k_cat<<<L_TOK, 256, 0, stream>>>(berthid, lp, rp, posl, posr, Acat);
    k_transcvt<<<dim3(26, 8), 256, 0, stream>>>(space_w, spaceT, 832, 256);
    k_transcvt<<<dim3(8, 8), 256, 0, stream>>>(wq, wqT, 256, 256);
    k_transcvt<<<dim3(8, 8), 256, 0, stream>>>(wk, wkT, 256, 256);
    k_transcvt<<<dim3(8, 8), 256, 0, stream>>>(wv, wvT, 256, 256);
    k_transcvt<<<dim3(8, 8), 256, 0, stream>>>(ewq, ewqT, 256, 256);
    k_transcvt<<<dim3(8, 8), 256, 0, stream>>>(ewk, ewkT, 256, 256);
    k_transcvt<<<dim3(8, 8), 256, 0, stream>>>(out_w, outwT, 256, 256);
    k_transcvt<<<dim3(16, 8), 256, 0, stream>>>(gate_w, gatewT, 512, 256);
    k_convw<<<768, 256, 0, stream>>>(conv1_w, c1T, 3, 256*256*3);
    k_convw<<<1280, 256, 0, stream>>>(conv2_w, c2T, 5, 256*256*5);
    k_cvt<<<1536, 256, 0, stream>>>(wih0, wih0c, 2*768*256);
    k_cvt<<<1536, 256, 0, stream>>>(whh0, whh0c, 2*768*256);
    k_cvt<<<3072, 256, 0, stream>>>(wih1, wih1c, 2*768*512);
    k_cvt<<<1536, 256, 0, stream>>>(whh1, whh1c, 2*768*256);
    k_ex<<<2048, 256, 0, stream>>>(entemb, et, exb);

    // proj -> xpad1 (data rows offset +1 row)
    k_gemm<<<dim3(256, 2), 256, 0, stream>>>(Acat, spaceT, space_b, xpad1,
        832, 16*832, 832, 18*256, 256, 256, 0);
    // conv1 -> xpad2 (data rows offset +2 rows), relu
    k_gemm<<<dim3(256, 2), 256, 0, stream>>>(xpad1, c1T, conv1_b, xpad2,
        768, 18*256, 256, 20*256, 256, 512, 1);
    // conv2 -> c2out, relu
    k_gemm<<<dim3(256, 2), 256, 0, stream>>>(xpad2, c2T, conv2_b, c2out,
        1280, 20*256, 256, 16*256, 256, 0, 1);
    k_pool<<<2048, 256, 0, stream>>>(c2out, segb);

    // qkv (+entity streams)
    k_gemm<<<dim3(16, 2), 256, 0, stream>>>(segb, wqT, b_q, qbuf, 256, 4096, 256, 4096, 256, 0, 0);
    k_gemm<<<dim3(16, 2), 256, 0, stream>>>(segb, wkT, b_k, kbuf, 256, 4096, 256, 4096, 256, 0, 0);
    k_gemm<<<dim3(16, 2), 256, 0, stream>>>(segb, wvT, b_v, vbuf, 256, 4096, 256, 4096, 256, 0, 0);
    k_gemm<<<dim3(16, 2), 256, 0, stream>>>(exb, ewqT, eb_q, qebuf, 256, 4096, 256, 4096, 256, 0, 0);
    k_gemm<<<dim3(16, 2), 256, 0, stream>>>(exb, ewkT, eb_k, kebuf, 256, 4096, 256, 4096, 256, 0, 0);
    k_vt<<<dim3(64, 8), 256, 0, stream>>>(vbuf, vtb);
    k_attn<<<dim3(32, 8), 256, 0, stream>>>(qbuf, kbuf, qebuf, kebuf, vtb, ctxb);

    // gated fusion
    k_gemm<<<dim3(16, 2), 256, 0, stream>>>(ctxb, outwT, out_b, gcat, 256, 4096, 256, 16*512, 512, 0, 0);
    k_copyseg<<<2048, 256, 0, stream>>>(segb, gcat);
    k_gemm<<<dim3(16, 2), 256, 0, stream>>>(gcat, gatewT, gate_b, gpb, 512, 16*512, 512, 4096, 256, 0, 0);
    k_fuse<<<2048, 256, 0, stream>>>(gpb, gcat, segb, fusb);

    // GRU layer 0
    k_gemm<<<dim3(16, 12), 256, 0, stream>>>(fusb, wih0c, bih0, gi0b, 256, 4096, 256, 16*1536, 1536, 0, 0);
    k_gru<<<2*GRU_NBLK, 512, 0, stream>>>(gi0b, whh0c, bhh0, l0b, l0b, 0);
    // GRU layer 1
    k_gemm<<<dim3(16, 12), 256, 0, stream>>>(l0b, wih1c, bih1, gi1b, 512, 16*512, 512, 16*1536, 1536, 0, 0);
    k_gru<<<2*GRU_NBLK, 512, 0, stream>>>(gi1b, whh1c, bhh1, md0, md1, 1);

    // finals
    k_f0<<<2048, 256, 0, stream>>>(md0, md1, myf, doutp);
    k_f1<<<1, 256, 0, stream>>>(myf, symi, sw1, sw2, scorec, smallf);
    k_f2<<<512, 256, 0, stream>>>(myf, smallf, doutp + (size_t)S_SEG*256);
}